// Round 1
// baseline (620.698 us; speedup 1.0000x reference)
//
#include <hip/hip_runtime.h>
#include <math.h>

#define B 1024
#define FRAMES 31
#define NFFT 2048
#define NH 256

// ---------------- K1: mean over 31 frames (memory-bound, float4) ----------------
__global__ __launch_bounds__(256) void k_frame_mean(const float* __restrict__ x,
                                                    float* __restrict__ xm) {
    int idx = blockIdx.x * 256 + threadIdx.x;      // float4 units: B*512 total
    int b = idx >> 9;
    int c = idx & 511;
    const float4* row = ((const float4*)x) + (size_t)b * (FRAMES * 512) + c;
    float4 a = {0.f, 0.f, 0.f, 0.f};
#pragma unroll
    for (int f = 0; f < FRAMES; ++f) {
        float4 v = row[(size_t)f * 512];
        a.x += v.x; a.y += v.y; a.z += v.z; a.w += v.w;
    }
    const float s = 1.0f / (float)FRAMES;
    a.x *= s; a.y *= s; a.z *= s; a.w *= s;
    ((float4*)xm)[idx] = a;
}

// ---------------- K2: M_partial[s][n][j] = sum_{k in split s} cos(2pi n k/2048) * W1[j][k]
// grid (128 n-tiles of 16, 4 k-splits of 512), 256 threads.
// thread: j0 = tid&63 handles j in {j0, j0+64, j0+128, j0+192}; ng = tid>>6 handles n = n0+4*ng+i.
__global__ __launch_bounds__(256) void k_build_M(const float* __restrict__ W1,
                                                 float* __restrict__ Mp) {
    __shared__ float costab[NFFT];
    const int tid = threadIdx.x;
    const float w0 = 6.28318530717958647692f / (float)NFFT;
    for (int i = tid; i < NFFT; i += 256)
        costab[i] = cosf(w0 * (float)i);
    __syncthreads();

    const int n0 = blockIdx.x * 16;
    const int k0 = blockIdx.y * 512;
    const int j0 = tid & 63;
    const int ng = tid >> 6;
    const int nb = n0 + ng * 4;

    const float* w1a = W1 + (size_t)(j0      ) * NFFT;
    const float* w1b = W1 + (size_t)(j0 +  64) * NFFT;
    const float* w1c = W1 + (size_t)(j0 + 128) * NFFT;
    const float* w1d = W1 + (size_t)(j0 + 192) * NFFT;

    float acc[4][4];
#pragma unroll
    for (int i = 0; i < 4; ++i)
#pragma unroll
        for (int q = 0; q < 4; ++q) acc[i][q] = 0.f;

    int step[4], cidx[4];
#pragma unroll
    for (int i = 0; i < 4; ++i) {
        step[i] = nb + i;
        cidx[i] = (step[i] * k0) & (NFFT - 1);
    }

    for (int k = k0; k < k0 + 512; ++k) {
        float wa = w1a[k], wb = w1b[k], wc = w1c[k], wd = w1d[k];
#pragma unroll
        for (int i = 0; i < 4; ++i) {
            float c = costab[cidx[i]];
            cidx[i] = (cidx[i] + step[i]) & (NFFT - 1);
            acc[i][0] = fmaf(c, wa, acc[i][0]);
            acc[i][1] = fmaf(c, wb, acc[i][1]);
            acc[i][2] = fmaf(c, wc, acc[i][2]);
            acc[i][3] = fmaf(c, wd, acc[i][3]);
        }
    }

    float* out = Mp + (size_t)blockIdx.y * (NFFT * NH);
#pragma unroll
    for (int i = 0; i < 4; ++i) {
        size_t r = (size_t)(nb + i) * NH;
        out[r + j0      ] = acc[i][0];
        out[r + j0 +  64] = acc[i][1];
        out[r + j0 + 128] = acc[i][2];
        out[r + j0 + 192] = acc[i][3];
    }
}

// ---------------- K2b: M = sum of 4 partials ----------------
__global__ __launch_bounds__(256) void k_reduce_M(const float* __restrict__ Mp,
                                                  float* __restrict__ M) {
    int idx = blockIdx.x * 256 + threadIdx.x;      // float4 units: 131072 total
    const float4* p = (const float4*)Mp;
    float4 a = p[idx];
    float4 b = p[idx + 131072];
    float4 c = p[idx + 2 * 131072];
    float4 d = p[idx + 3 * 131072];
    a.x += b.x + c.x + d.x;
    a.y += b.y + c.y + d.y;
    a.z += b.z + c.z + d.z;
    a.w += b.w + c.w + d.w;
    ((float4*)M)[idx] = a;
}

// ---------------- K3: y1 = relu(xm @ M + b1), 4 batch rows per block ----------------
__global__ __launch_bounds__(256) void k_layer1(const float* __restrict__ xm,
                                                const float* __restrict__ M,
                                                const float* __restrict__ b1,
                                                float* __restrict__ y1) {
    __shared__ float xs[NFFT * 4];   // [n][4 batch rows] interleaved, 32 KB
    const int tid = threadIdx.x;
    const int b0 = blockIdx.x * 4;
    for (int i = tid; i < NFFT * 4; i += 256) {
        int bi = i & 3;
        int n  = i >> 2;
        xs[i] = xm[(size_t)(b0 + bi) * NFFT + n];
    }
    __syncthreads();

    float a0 = 0.f, a1 = 0.f, a2 = 0.f, a3 = 0.f;
    for (int n = 0; n < NFFT; ++n) {
        float mv = M[(size_t)n * NH + tid];       // coalesced across lanes
        float4 xv = *((const float4*)(xs + n * 4)); // wave-uniform broadcast
        a0 = fmaf(xv.x, mv, a0);
        a1 = fmaf(xv.y, mv, a1);
        a2 = fmaf(xv.z, mv, a2);
        a3 = fmaf(xv.w, mv, a3);
    }
    float bb = b1[tid];
    y1[(size_t)(b0 + 0) * NH + tid] = fmaxf(a0 + bb, 0.f);
    y1[(size_t)(b0 + 1) * NH + tid] = fmaxf(a1 + bb, 0.f);
    y1[(size_t)(b0 + 2) * NH + tid] = fmaxf(a2 + bb, 0.f);
    y1[(size_t)(b0 + 3) * NH + tid] = fmaxf(a3 + bb, 0.f);
}

// ---------------- K4: out = sigmoid(relu(y1 @ W2^T + b2) @ W3^T + b3), one block per batch row
__global__ __launch_bounds__(256) void k_head(const float* __restrict__ y1,
                                              const float* __restrict__ W2,
                                              const float* __restrict__ b2,
                                              const float* __restrict__ W3,
                                              const float* __restrict__ b3,
                                              float* __restrict__ out) {
    __shared__ float ys[NH];
    __shared__ float red[NH];
    const int tid = threadIdx.x;
    const int b = blockIdx.x;
    ys[tid] = y1[(size_t)b * NH + tid];
    __syncthreads();

    const float4* w2 = (const float4*)(W2 + (size_t)tid * NH);
    const float4* yv4 = (const float4*)ys;
    float acc = 0.f;
#pragma unroll 8
    for (int n4 = 0; n4 < NH / 4; ++n4) {
        float4 w = w2[n4];
        float4 y = yv4[n4];
        acc = fmaf(w.x, y.x, acc);
        acc = fmaf(w.y, y.y, acc);
        acc = fmaf(w.z, y.z, acc);
        acc = fmaf(w.w, y.w, acc);
    }
    float h2 = fmaxf(acc + b2[tid], 0.f);
    red[tid] = h2 * W3[tid];
    __syncthreads();
#pragma unroll
    for (int s = 128; s > 0; s >>= 1) {
        if (tid < s) red[tid] += red[tid + s];
        __syncthreads();
    }
    if (tid == 0) {
        float z = red[0] + b3[0];
        out[b] = 1.f / (1.f + expf(-z));
    }
}

extern "C" void kernel_launch(void* const* d_in, const int* in_sizes, int n_in,
                              void* d_out, int out_size, void* d_ws, size_t ws_size,
                              hipStream_t stream) {
    const float* x  = (const float*)d_in[0];
    const float* W1 = (const float*)d_in[1];
    const float* b1 = (const float*)d_in[2];
    const float* W2 = (const float*)d_in[3];
    const float* b2 = (const float*)d_in[4];
    const float* W3 = (const float*)d_in[5];
    const float* b3 = (const float*)d_in[6];
    float* out = (float*)d_out;

    char* ws = (char*)d_ws;
    float* xm = (float*)(ws);                     // 8 MB  [1024][2048]
    float* Mp = (float*)(ws + (8u  << 20));       // 8 MB  [4][2048][256] partials
    float* y1 = (float*)(ws + (8u  << 20));       // 1 MB  (reuses Mp region after K2b)
    float* M  = (float*)(ws + (16u << 20));       // 2 MB  [2048][256]

    hipLaunchKernelGGL(k_frame_mean, dim3(B * 512 / 256), dim3(256), 0, stream, x, xm);
    hipLaunchKernelGGL(k_build_M,    dim3(128, 4),        dim3(256), 0, stream, W1, Mp);
    hipLaunchKernelGGL(k_reduce_M,   dim3(512),           dim3(256), 0, stream, Mp, M);
    hipLaunchKernelGGL(k_layer1,     dim3(B / 4),         dim3(256), 0, stream, xm, M, b1, y1);
    hipLaunchKernelGGL(k_head,       dim3(B),             dim3(256), 0, stream, y1, W2, b2, W3, b3, out);
}

// Round 2
// 426.879 us; speedup vs baseline: 1.4540x; 1.4540x over previous
//
#include <hip/hip_runtime.h>
#include <math.h>

#define B 1024
#define FRAMES 31
#define NFFT 2048
#define NH 256
#define TWO_PI 6.28318530717958647692f

#define KSPLIT 16
#define KRANGE (NFFT / KSPLIT)   // 128
#define BT 32                    // batch tile per gemm block
#define JP 260                   // padded j-pitch for W1s tile (16B-aligned rows, ~2-way banks)
#define HP 36                    // padded b-pitch for h tile

// ---------------- K12: frame-mean + 2048-pt FFT (keep real part) ----------------
// One block per batch row. Mean over 31 frames (HBM-bound, coalesced), then
// in-LDS radix-2 DIT FFT, write Re(X) to h[b][0..2047].
__global__ __launch_bounds__(256) void k_mean_fft(const float* __restrict__ x,
                                                  float* __restrict__ h) {
    __shared__ float re[NFFT];
    __shared__ float im[NFFT];
    __shared__ float ct[NFFT];
    const int tid = threadIdx.x;
    const int b = blockIdx.x;
    const float* xr = x + (size_t)b * (FRAMES * NFFT);

    // cos table: ct[i] = cos(2*pi*i/2048)
#pragma unroll
    for (int s = 0; s < 8; ++s) {
        int i = tid + (s << 8);
        ct[i] = cosf(TWO_PI * (float)i / (float)NFFT);
    }

    // frame mean (coalesced scalar loads, 8 accumulators/thread)
    float acc[8];
#pragma unroll
    for (int s = 0; s < 8; ++s) acc[s] = 0.f;
    for (int f = 0; f < FRAMES; ++f) {
        const float* fr = xr + f * NFFT;
#pragma unroll
        for (int s = 0; s < 8; ++s) acc[s] += fr[tid + (s << 8)];
    }
    const float inv = 1.0f / (float)FRAMES;
#pragma unroll
    for (int s = 0; s < 8; ++s) {
        int n = tid + (s << 8);
        int rv = __brev((unsigned)n) >> 21;   // 11-bit reverse
        re[rv] = acc[s] * inv;
        im[rv] = 0.f;
    }
    __syncthreads();

    // radix-2 DIT stages, w_m^j = exp(-2*pi*i*j/m)
    for (int stage = 1; stage <= 11; ++stage) {
        const int half = 1 << (stage - 1);
        const int tsh = 11 - stage;
#pragma unroll
        for (int s = 0; s < 4; ++s) {
            int idx = tid + (s << 8);                       // butterfly id 0..1023
            int j = idx & (half - 1);
            int base = ((idx >> (stage - 1)) << stage) + j;
            int ti = j << tsh;
            float wr = ct[ti];
            float wi = -ct[(ti + 1536) & (NFFT - 1)];       // -sin
            float ar = re[base], ai = im[base];
            float br = re[base + half], bi = im[base + half];
            float tr = wr * br - wi * bi;
            float tq = wr * bi + wi * br;
            re[base] = ar + tr;
            im[base] = ai + tq;
            re[base + half] = ar - tr;
            im[base + half] = ai - tq;
        }
        __syncthreads();
    }

    float* hr = h + (size_t)b * NFFT;
#pragma unroll
    for (int s = 0; s < 8; ++s)
        hr[tid + (s << 8)] = re[tid + (s << 8)];
}

// ---------------- K3: partial GEMM  yp[sp][b][j] = sum_{k in split} h[b][k]*W1[j][k]
// grid (32 b-tiles, 16 k-splits), 256 threads. Per thread: 8 b x 4 j register tile.
__global__ __launch_bounds__(256) void k_gemm1(const float* __restrict__ h,
                                               const float* __restrict__ W1,
                                               float* __restrict__ yp) {
    __shared__ float W1s[32 * JP];   // [k 0..31][j 0..255], pitch 260
    __shared__ float hs[32 * HP];    // [k 0..31][b 0..31],  pitch 36
    const int tid = threadIdx.x;
    const int b0 = blockIdx.x * BT;
    const int kb0 = blockIdx.y * KRANGE;

    const int j0 = (tid & 63) * 4;
    const int bo = (tid >> 6) * 8;

    float acc[8][4];
#pragma unroll
    for (int i = 0; i < 8; ++i)
#pragma unroll
        for (int q = 0; q < 4; ++q) acc[i][q] = 0.f;

    for (int kc = 0; kc < KRANGE; kc += 32) {
        const int kb = kb0 + kc;
        // stage W1 tile (256 j x 32 k), transpose into [k][j]
#pragma unroll
        for (int s = 0; s < 8; ++s) {
            int f = tid + (s << 8);      // 0..2047
            int j = f >> 3;
            int k4 = f & 7;
            float4 v = *(const float4*)(W1 + (size_t)j * NFFT + kb + k4 * 4);
            W1s[(k4 * 4 + 0) * JP + j] = v.x;
            W1s[(k4 * 4 + 1) * JP + j] = v.y;
            W1s[(k4 * 4 + 2) * JP + j] = v.z;
            W1s[(k4 * 4 + 3) * JP + j] = v.w;
        }
        // stage h tile (32 b x 32 k), transpose into [k][b]
        {
            int bb = tid >> 3;
            int k4 = tid & 7;
            float4 v = *(const float4*)(h + (size_t)(b0 + bb) * NFFT + kb + k4 * 4);
            hs[(k4 * 4 + 0) * HP + bb] = v.x;
            hs[(k4 * 4 + 1) * HP + bb] = v.y;
            hs[(k4 * 4 + 2) * HP + bb] = v.z;
            hs[(k4 * 4 + 3) * HP + bb] = v.w;
        }
        __syncthreads();

#pragma unroll 8
        for (int k = 0; k < 32; ++k) {
            float4 w = *(const float4*)&W1s[k * JP + j0];
            float4 hA = *(const float4*)&hs[k * HP + bo];
            float4 hB = *(const float4*)&hs[k * HP + bo + 4];
            acc[0][0] = fmaf(hA.x, w.x, acc[0][0]); acc[0][1] = fmaf(hA.x, w.y, acc[0][1]);
            acc[0][2] = fmaf(hA.x, w.z, acc[0][2]); acc[0][3] = fmaf(hA.x, w.w, acc[0][3]);
            acc[1][0] = fmaf(hA.y, w.x, acc[1][0]); acc[1][1] = fmaf(hA.y, w.y, acc[1][1]);
            acc[1][2] = fmaf(hA.y, w.z, acc[1][2]); acc[1][3] = fmaf(hA.y, w.w, acc[1][3]);
            acc[2][0] = fmaf(hA.z, w.x, acc[2][0]); acc[2][1] = fmaf(hA.z, w.y, acc[2][1]);
            acc[2][2] = fmaf(hA.z, w.z, acc[2][2]); acc[2][3] = fmaf(hA.z, w.w, acc[2][3]);
            acc[3][0] = fmaf(hA.w, w.x, acc[3][0]); acc[3][1] = fmaf(hA.w, w.y, acc[3][1]);
            acc[3][2] = fmaf(hA.w, w.z, acc[3][2]); acc[3][3] = fmaf(hA.w, w.w, acc[3][3]);
            acc[4][0] = fmaf(hB.x, w.x, acc[4][0]); acc[4][1] = fmaf(hB.x, w.y, acc[4][1]);
            acc[4][2] = fmaf(hB.x, w.z, acc[4][2]); acc[4][3] = fmaf(hB.x, w.w, acc[4][3]);
            acc[5][0] = fmaf(hB.y, w.x, acc[5][0]); acc[5][1] = fmaf(hB.y, w.y, acc[5][1]);
            acc[5][2] = fmaf(hB.y, w.z, acc[5][2]); acc[5][3] = fmaf(hB.y, w.w, acc[5][3]);
            acc[6][0] = fmaf(hB.z, w.x, acc[6][0]); acc[6][1] = fmaf(hB.z, w.y, acc[6][1]);
            acc[6][2] = fmaf(hB.z, w.z, acc[6][2]); acc[6][3] = fmaf(hB.z, w.w, acc[6][3]);
            acc[7][0] = fmaf(hB.w, w.x, acc[7][0]); acc[7][1] = fmaf(hB.w, w.y, acc[7][1]);
            acc[7][2] = fmaf(hB.w, w.z, acc[7][2]); acc[7][3] = fmaf(hB.w, w.w, acc[7][3]);
        }
        __syncthreads();
    }

    float* yo = yp + (size_t)blockIdx.y * (B * NH);
#pragma unroll
    for (int i = 0; i < 8; ++i) {
        float4 v = make_float4(acc[i][0], acc[i][1], acc[i][2], acc[i][3]);
        *(float4*)(yo + (size_t)(b0 + bo + i) * NH + j0) = v;
    }
}

// ---------------- K3b: y1 = relu(sum of partials + b1) ----------------
__global__ __launch_bounds__(256) void k_reduce_relu(const float* __restrict__ yp,
                                                     const float* __restrict__ b1,
                                                     float* __restrict__ y1) {
    int f = blockIdx.x * 256 + threadIdx.x;   // float4 index, 65536 total
    const float4* p = (const float4*)yp;
    float4 a = p[f];
#pragma unroll
    for (int s = 1; s < KSPLIT; ++s) {
        float4 v = p[f + s * (B * NH / 4)];
        a.x += v.x; a.y += v.y; a.z += v.z; a.w += v.w;
    }
    float4 bb = ((const float4*)b1)[f & 63];
    a.x = fmaxf(a.x + bb.x, 0.f);
    a.y = fmaxf(a.y + bb.y, 0.f);
    a.z = fmaxf(a.z + bb.z, 0.f);
    a.w = fmaxf(a.w + bb.w, 0.f);
    ((float4*)y1)[f] = a;
}

// ---------------- K4: out = sigmoid(relu(y1 @ W2^T + b2) @ W3^T + b3), 4 rows/block
__global__ __launch_bounds__(256) void k_head(const float* __restrict__ y1,
                                              const float* __restrict__ W2,
                                              const float* __restrict__ b2,
                                              const float* __restrict__ W3,
                                              const float* __restrict__ b3,
                                              float* __restrict__ out) {
    __shared__ float ys[4 * NH];
    __shared__ float red[4 * NH];
    const int tid = threadIdx.x;
    const int b0 = blockIdx.x * 4;
    ((float4*)ys)[tid] = ((const float4*)(y1 + (size_t)b0 * NH))[tid];
    __syncthreads();

    const float4* w2 = (const float4*)(W2 + (size_t)tid * NH);
    float a0 = 0.f, a1 = 0.f, a2 = 0.f, a3 = 0.f;
#pragma unroll 8
    for (int n4 = 0; n4 < NH / 4; ++n4) {
        float4 w = w2[n4];
        float4 v0 = ((const float4*)ys)[n4];
        float4 v1 = ((const float4*)ys)[64 + n4];
        float4 v2 = ((const float4*)ys)[128 + n4];
        float4 v3 = ((const float4*)ys)[192 + n4];
        a0 = fmaf(w.x, v0.x, a0); a0 = fmaf(w.y, v0.y, a0);
        a0 = fmaf(w.z, v0.z, a0); a0 = fmaf(w.w, v0.w, a0);
        a1 = fmaf(w.x, v1.x, a1); a1 = fmaf(w.y, v1.y, a1);
        a1 = fmaf(w.z, v1.z, a1); a1 = fmaf(w.w, v1.w, a1);
        a2 = fmaf(w.x, v2.x, a2); a2 = fmaf(w.y, v2.y, a2);
        a2 = fmaf(w.z, v2.z, a2); a2 = fmaf(w.w, v2.w, a2);
        a3 = fmaf(w.x, v3.x, a3); a3 = fmaf(w.y, v3.y, a3);
        a3 = fmaf(w.z, v3.z, a3); a3 = fmaf(w.w, v3.w, a3);
    }
    float w3 = W3[tid];
    float bb = b2[tid];
    red[tid]       = fmaxf(a0 + bb, 0.f) * w3;
    red[256 + tid] = fmaxf(a1 + bb, 0.f) * w3;
    red[512 + tid] = fmaxf(a2 + bb, 0.f) * w3;
    red[768 + tid] = fmaxf(a3 + bb, 0.f) * w3;
    __syncthreads();
    for (int s = 128; s > 0; s >>= 1) {
        if (tid < s) {
#pragma unroll
            for (int q = 0; q < 4; ++q)
                red[q * 256 + tid] += red[q * 256 + tid + s];
        }
        __syncthreads();
    }
    if (tid < 4)
        out[b0 + tid] = 1.f / (1.f + expf(-(red[tid * 256] + b3[0])));
}

extern "C" void kernel_launch(void* const* d_in, const int* in_sizes, int n_in,
                              void* d_out, int out_size, void* d_ws, size_t ws_size,
                              hipStream_t stream) {
    const float* x  = (const float*)d_in[0];
    const float* W1 = (const float*)d_in[1];
    const float* b1 = (const float*)d_in[2];
    const float* W2 = (const float*)d_in[3];
    const float* b2 = (const float*)d_in[4];
    const float* W3 = (const float*)d_in[5];
    const float* b3 = (const float*)d_in[6];
    float* out = (float*)d_out;

    char* ws = (char*)d_ws;
    float* h  = (float*)(ws);                  //  8 MB  [1024][2048]
    float* yp = (float*)(ws + (8u  << 20));    // 16 MB  [16][1024][256] partials
    float* y1 = (float*)(ws + (24u << 20));    //  1 MB  [1024][256]

    hipLaunchKernelGGL(k_mean_fft,    dim3(B),       dim3(256), 0, stream, x, h);
    hipLaunchKernelGGL(k_gemm1,       dim3(32, 16),  dim3(256), 0, stream, h, W1, yp);
    hipLaunchKernelGGL(k_reduce_relu, dim3(256),     dim3(256), 0, stream, yp, b1, y1);
    hipLaunchKernelGGL(k_head,        dim3(256),     dim3(256), 0, stream, y1, W2, b2, W3, b3, out);
}